// Round 1
// baseline (365.780 us; speedup 1.0000x reference)
//
#include <hip/hip_runtime.h>

// MentionRankingModel: h_a/h_p embedding-bag + tanh + linear scoring into
// a 512x512 score matrix (diag = eps scores, strict lower tri = ana scores).

static constexpr int NM = 512;                    // mentions
static constexpr int NF = 20;                     // features per mention/candidate
static constexpr int NC = NM * (NM - 1) / 2;      // 130816 candidates
static constexpr int H  = 128;                    // HA == HP == 128

// ---------------------------------------------------------------------------
// Zero the 512x512 output (harness poisons d_out with 0xAA before each call).
__global__ __launch_bounds__(256) void zero_out_kernel(float4* __restrict__ out) {
    out[blockIdx.x * 256 + threadIdx.x] = make_float4(0.f, 0.f, 0.f, 0.f);
}

__device__ __forceinline__ float reduce_half32(float v) {
    // Sum across each 32-lane half of the 64-lane wave (xor masks <32 stay in-half).
    #pragma unroll
    for (int m = 16; m; m >>= 1) v += __shfl_xor(v, m, 64);
    return v;
}

// ---------------------------------------------------------------------------
// Mentions: h_a[j] = tanh(sum_f emb_a[phi_a[j,f]] + bias_a)  (idx 0 = padding)
// Only two scalars per mention survive:
//   out[j,j]  = h_a[j] . w_eps + b_eps         (diagonal eps score)
//   apart[j]  = h_a[j] . w_ana[:128]           (reused by every candidate row)
// 2 mentions per wave; each lane owns a float4 column slice (k = lane&31).
__global__ __launch_bounds__(256) void mention_kernel(
        const int*   __restrict__ phi_a,  const float* __restrict__ emb_a,
        const float* __restrict__ bias_a, const float* __restrict__ w_eps,
        const float* __restrict__ b_eps,  const float* __restrict__ w_ana,
        float* __restrict__ out, float* __restrict__ apart) {
    const int lane = threadIdx.x & 63;
    const int half = lane >> 5;
    const int k    = lane & 31;
    const int wave = (blockIdx.x * 256 + threadIdx.x) >> 6;
    const int m    = wave * 2 + half;          // grid sized exactly: m in [0,512)

    float4 acc = *(const float4*)(bias_a + k * 4);
    const int* prow = phi_a + m * NF;
    #pragma unroll
    for (int f = 0; f < NF; ++f) {
        int idx = prow[f];
        if (idx != 0) {                        // padding_idx = 0 contributes zero
            float4 v = *(const float4*)(emb_a + idx * H + k * 4);
            acc.x += v.x; acc.y += v.y; acc.z += v.z; acc.w += v.w;
        }
    }
    float4 h;
    h.x = tanhf(acc.x); h.y = tanhf(acc.y); h.z = tanhf(acc.z); h.w = tanhf(acc.w);

    float4 we = *(const float4*)(w_eps + k * 4);
    float4 wa = *(const float4*)(w_ana + k * 4);   // first HA half of w_ana
    float eps = h.x*we.x + h.y*we.y + h.z*we.z + h.w*we.w;
    float ap  = h.x*wa.x + h.y*wa.y + h.z*wa.z + h.w*wa.w;
    eps = reduce_half32(eps);
    ap  = reduce_half32(ap);
    if (k == 0) {
        out[m * NM + m] = eps + b_eps[0];
        apart[m] = ap;
    }
}

// ---------------------------------------------------------------------------
// Candidates: h_p[c] = tanh(sum_f emb_p[phi_p[c,f]] + bias_p)
//   score = apart[row(c)] + h_p[c] . w_ana[128:] + b_ana
//   out[row, col] = score  (strict lower triangle, row-major candidate order)
// 2 candidates per wave (one per 32-lane half), float4 per lane:
// each gather instruction moves 64 lanes x 16B = two full contiguous 512B rows.
__global__ __launch_bounds__(256) void cand_kernel(
        const int*   __restrict__ phi_p,  const float* __restrict__ emb_p,
        const float* __restrict__ bias_p, const float* __restrict__ w_ana,
        const float* __restrict__ b_ana,  const float* __restrict__ apart,
        float* __restrict__ out) {
    const int lane = threadIdx.x & 63;
    const int half = lane >> 5;
    const int k    = lane & 31;
    const int wave = (blockIdx.x * 256 + threadIdx.x) >> 6;
    const int c    = wave * 2 + half;          // grid sized exactly: c in [0,130816)

    float4 acc = *(const float4*)(bias_p + k * 4);
    const int* prow = phi_p + c * NF;
    #pragma unroll
    for (int f = 0; f < NF; ++f) {
        int idx = prow[f];
        if (idx != 0) {
            float4 v = *(const float4*)(emb_p + idx * H + k * 4);
            acc.x += v.x; acc.y += v.y; acc.z += v.z; acc.w += v.w;
        }
    }
    float4 h;
    h.x = tanhf(acc.x); h.y = tanhf(acc.y); h.z = tanhf(acc.z); h.w = tanhf(acc.w);

    float4 w2 = *(const float4*)(w_ana + H + k * 4);  // second HP half of w_ana
    float part = h.x*w2.x + h.y*w2.y + h.z*w2.z + h.w*w2.w;
    part = reduce_half32(part);

    if (k == 0) {
        // row j: largest j with j*(j-1)/2 <= c ; exact via fp32 sqrt + fixup
        float s = sqrtf((float)(8 * c + 1));
        int j = (int)((1.0f + s) * 0.5f);
        while (j * (j + 1) / 2 <= c) ++j;
        while (j * (j - 1) / 2 > c) --j;
        int col = c - j * (j - 1) / 2;
        out[j * NM + col] = part + apart[j] + b_ana[0];
    }
}

// ---------------------------------------------------------------------------
extern "C" void kernel_launch(void* const* d_in, const int* in_sizes, int n_in,
                              void* d_out, int out_size, void* d_ws, size_t ws_size,
                              hipStream_t stream) {
    const int*   phi_a  = (const int*)  d_in[0];
    const int*   phi_p  = (const int*)  d_in[1];
    const float* emb_a  = (const float*)d_in[2];
    const float* bias_a = (const float*)d_in[3];
    const float* emb_p  = (const float*)d_in[4];
    const float* bias_p = (const float*)d_in[5];
    const float* w_eps  = (const float*)d_in[6];
    const float* b_eps  = (const float*)d_in[7];
    const float* w_ana  = (const float*)d_in[8];
    const float* b_ana  = (const float*)d_in[9];
    float* out   = (float*)d_out;
    float* apart = (float*)d_ws;               // 512 floats of scratch

    // 262144 floats = 65536 float4 -> 256 blocks
    zero_out_kernel<<<(NM * NM) / (4 * 256), 256, 0, stream>>>((float4*)out);
    // 512 mentions, 2/wave, 4 waves/block -> 64 blocks (exact)
    mention_kernel<<<NM / 2 / 4, 256, 0, stream>>>(phi_a, emb_a, bias_a, w_eps,
                                                   b_eps, w_ana, out, apart);
    // 130816 candidates, 2/wave, 4 waves/block -> 16352 blocks (exact)
    cand_kernel<<<NC / 2 / 4, 256, 0, stream>>>(phi_p, emb_p, bias_p, w_ana,
                                                b_ana, apart, out);
}

// Round 2
// 297.226 us; speedup vs baseline: 1.2306x; 1.2306x over previous
//
#include <hip/hip_runtime.h>

// MentionRankingModel: h_a/h_p embedding-bag + tanh + linear scoring into
// a 512x512 score matrix (diag = eps scores, strict lower tri = ana scores).
//
// R1 insight: cand gather is BW-bound on the L2-miss path (636 MB FETCH,
// 3.3 TB/s). Compress emb_p to bf16 in d_ws each call (absmax margin 13x
// allows it) -> halves gather bytes. 4 candidates/wave, 256 B rows.

static constexpr int NM = 512;                    // mentions
static constexpr int NF = 20;                     // features per mention/candidate
static constexpr int NC = NM * (NM - 1) / 2;      // 130816 candidates
static constexpr int H  = 128;                    // HA == HP == 128
static constexpr int EMBP_ROWS = 200001;
static constexpr long long EMBP_ELEMS = (long long)EMBP_ROWS * H;  // 25,600,128
static constexpr int CVT_GROUPS = (int)(EMBP_ELEMS / 8);           // 3,200,016

// ---------------------------------------------------------------------------
// Zero the 512x512 output (harness poisons d_out with 0xAA before each call).
__global__ __launch_bounds__(256) void zero_out_kernel(float4* __restrict__ out) {
    out[blockIdx.x * 256 + threadIdx.x] = make_float4(0.f, 0.f, 0.f, 0.f);
}

// ---------------------------------------------------------------------------
// Convert emb_p f32 -> bf16 (RNE), 8 elements/thread: 32 B read, 16 B write.
__device__ __forceinline__ unsigned bf16_rne(float f) {
    unsigned u = __float_as_uint(f);
    return (u + 0x7fffu + ((u >> 16) & 1u)) >> 16;
}

__global__ __launch_bounds__(256) void cvt_bf16_kernel(
        const float* __restrict__ src, uint4* __restrict__ dst, int ngroups) {
    int i = blockIdx.x * 256 + threadIdx.x;
    if (i >= ngroups) return;
    const float4* s = (const float4*)src + (size_t)i * 2;
    float4 a = s[0], b = s[1];
    uint4 o;
    o.x = bf16_rne(a.x) | (bf16_rne(a.y) << 16);
    o.y = bf16_rne(a.z) | (bf16_rne(a.w) << 16);
    o.z = bf16_rne(b.x) | (bf16_rne(b.y) << 16);
    o.w = bf16_rne(b.z) | (bf16_rne(b.w) << 16);
    dst[i] = o;
}

__device__ __forceinline__ float reduce_half32(float v) {
    #pragma unroll
    for (int m = 16; m; m >>= 1) v += __shfl_xor(v, m, 64);
    return v;
}

// ---------------------------------------------------------------------------
// Mentions (f32 path, tiny): out[j,j] = h_a[j].w_eps + b_eps ;
// apart[j] = h_a[j].w_ana[:128]. 2 mentions/wave, float4/lane.
__global__ __launch_bounds__(256) void mention_kernel(
        const int*   __restrict__ phi_a,  const float* __restrict__ emb_a,
        const float* __restrict__ bias_a, const float* __restrict__ w_eps,
        const float* __restrict__ b_eps,  const float* __restrict__ w_ana,
        float* __restrict__ out, float* __restrict__ apart) {
    const int lane = threadIdx.x & 63;
    const int half = lane >> 5;
    const int k    = lane & 31;
    const int wave = (blockIdx.x * 256 + threadIdx.x) >> 6;
    const int m    = wave * 2 + half;

    float4 acc = *(const float4*)(bias_a + k * 4);
    const int* prow = phi_a + m * NF;
    #pragma unroll
    for (int f = 0; f < NF; ++f) {
        int idx = prow[f];
        if (idx != 0) {                        // padding_idx = 0 contributes zero
            float4 v = *(const float4*)(emb_a + idx * H + k * 4);
            acc.x += v.x; acc.y += v.y; acc.z += v.z; acc.w += v.w;
        }
    }
    float4 h;
    h.x = tanhf(acc.x); h.y = tanhf(acc.y); h.z = tanhf(acc.z); h.w = tanhf(acc.w);

    float4 we = *(const float4*)(w_eps + k * 4);
    float4 wa = *(const float4*)(w_ana + k * 4);
    float eps = h.x*we.x + h.y*we.y + h.z*we.z + h.w*we.w;
    float ap  = h.x*wa.x + h.y*wa.y + h.z*wa.z + h.w*wa.w;
    eps = reduce_half32(eps);
    ap  = reduce_half32(ap);
    if (k == 0) {
        out[m * NM + m] = eps + b_eps[0];
        apart[m] = ap;
    }
}

// ---------------------------------------------------------------------------
// Candidates, bf16 table: 4 candidates/wave, 16 lanes each holding 8 elems.
// Each gather instruction: 64 lanes x 16 B = four full contiguous 256 B rows.
__global__ __launch_bounds__(256) void cand_kernel_bf16(
        const int* __restrict__ phi_p, const unsigned* __restrict__ embp,
        const float* __restrict__ bias_p, const float* __restrict__ w_ana,
        const float* __restrict__ b_ana, const float* __restrict__ apart,
        float* __restrict__ out) {
    const int lane = threadIdx.x & 63;
    const int g    = lane >> 4;
    const int k    = lane & 15;
    const int wave = (blockIdx.x * 256 + threadIdx.x) >> 6;
    const int c    = wave * 4 + g;             // grid exact: c in [0,130816)

    float4 b0 = *(const float4*)(bias_p + k * 8);
    float4 b1 = *(const float4*)(bias_p + k * 8 + 4);
    float a0 = b0.x, a1 = b0.y, a2 = b0.z, a3 = b0.w;
    float a4 = b1.x, a5 = b1.y, a6 = b1.z, a7 = b1.w;

    const int* prow = phi_p + c * NF;
    #pragma unroll
    for (int f = 0; f < NF; ++f) {
        int idx = prow[f];
        uint4 u = *(const uint4*)(embp + (size_t)idx * (H / 2) + k * 4);
        if (idx == 0) { u.x = 0; u.y = 0; u.z = 0; u.w = 0; }  // padding row
        a0 += __uint_as_float(u.x << 16); a1 += __uint_as_float(u.x & 0xffff0000u);
        a2 += __uint_as_float(u.y << 16); a3 += __uint_as_float(u.y & 0xffff0000u);
        a4 += __uint_as_float(u.z << 16); a5 += __uint_as_float(u.z & 0xffff0000u);
        a6 += __uint_as_float(u.w << 16); a7 += __uint_as_float(u.w & 0xffff0000u);
    }

    float4 w0 = *(const float4*)(w_ana + H + k * 8);
    float4 w1 = *(const float4*)(w_ana + H + k * 8 + 4);
    float part = tanhf(a0)*w0.x + tanhf(a1)*w0.y + tanhf(a2)*w0.z + tanhf(a3)*w0.w
               + tanhf(a4)*w1.x + tanhf(a5)*w1.y + tanhf(a6)*w1.z + tanhf(a7)*w1.w;
    #pragma unroll
    for (int m = 8; m; m >>= 1) part += __shfl_xor(part, m, 64);  // within 16-group

    if (k == 0) {
        float s = sqrtf((float)(8 * c + 1));
        int j = (int)((1.0f + s) * 0.5f);
        while (j * (j + 1) / 2 <= c) ++j;
        while (j * (j - 1) / 2 > c) --j;
        int col = c - j * (j - 1) / 2;
        out[j * NM + col] = part + apart[j] + b_ana[0];
    }
}

// ---------------------------------------------------------------------------
// f32 fallback (proven R1 kernel) in case ws_size can't hold the bf16 table.
__global__ __launch_bounds__(256) void cand_kernel_f32(
        const int*   __restrict__ phi_p,  const float* __restrict__ emb_p,
        const float* __restrict__ bias_p, const float* __restrict__ w_ana,
        const float* __restrict__ b_ana,  const float* __restrict__ apart,
        float* __restrict__ out) {
    const int lane = threadIdx.x & 63;
    const int half = lane >> 5;
    const int k    = lane & 31;
    const int wave = (blockIdx.x * 256 + threadIdx.x) >> 6;
    const int c    = wave * 2 + half;

    float4 acc = *(const float4*)(bias_p + k * 4);
    const int* prow = phi_p + c * NF;
    #pragma unroll
    for (int f = 0; f < NF; ++f) {
        int idx = prow[f];
        if (idx != 0) {
            float4 v = *(const float4*)(emb_p + idx * H + k * 4);
            acc.x += v.x; acc.y += v.y; acc.z += v.z; acc.w += v.w;
        }
    }
    float4 h;
    h.x = tanhf(acc.x); h.y = tanhf(acc.y); h.z = tanhf(acc.z); h.w = tanhf(acc.w);

    float4 w2 = *(const float4*)(w_ana + H + k * 4);
    float part = h.x*w2.x + h.y*w2.y + h.z*w2.z + h.w*w2.w;
    part = reduce_half32(part);

    if (k == 0) {
        float s = sqrtf((float)(8 * c + 1));
        int j = (int)((1.0f + s) * 0.5f);
        while (j * (j + 1) / 2 <= c) ++j;
        while (j * (j - 1) / 2 > c) --j;
        int col = c - j * (j - 1) / 2;
        out[j * NM + col] = part + apart[j] + b_ana[0];
    }
}

// ---------------------------------------------------------------------------
extern "C" void kernel_launch(void* const* d_in, const int* in_sizes, int n_in,
                              void* d_out, int out_size, void* d_ws, size_t ws_size,
                              hipStream_t stream) {
    const int*   phi_a  = (const int*)  d_in[0];
    const int*   phi_p  = (const int*)  d_in[1];
    const float* emb_a  = (const float*)d_in[2];
    const float* bias_a = (const float*)d_in[3];
    const float* emb_p  = (const float*)d_in[4];
    const float* bias_p = (const float*)d_in[5];
    const float* w_eps  = (const float*)d_in[6];
    const float* b_eps  = (const float*)d_in[7];
    const float* w_ana  = (const float*)d_in[8];
    const float* b_ana  = (const float*)d_in[9];
    float* out   = (float*)d_out;
    float* apart = (float*)d_ws;                       // 512 floats

    const size_t need = 4096 + (size_t)EMBP_ELEMS * 2; // apart pad + bf16 table
    const bool use_bf16 = ws_size >= need;

    zero_out_kernel<<<(NM * NM) / (4 * 256), 256, 0, stream>>>((float4*)out);

    if (use_bf16) {
        unsigned* embp16 = (unsigned*)((char*)d_ws + 4096);
        cvt_bf16_kernel<<<(CVT_GROUPS + 255) / 256, 256, 0, stream>>>(
            emb_p, (uint4*)embp16, CVT_GROUPS);
        mention_kernel<<<NM / 2 / 4, 256, 0, stream>>>(phi_a, emb_a, bias_a, w_eps,
                                                       b_eps, w_ana, out, apart);
        // 130816 candidates, 4/wave, 4 waves/block -> 8176 blocks (exact)
        cand_kernel_bf16<<<NC / 4 / 4, 256, 0, stream>>>(phi_p, embp16, bias_p,
                                                         w_ana, b_ana, apart, out);
    } else {
        mention_kernel<<<NM / 2 / 4, 256, 0, stream>>>(phi_a, emb_a, bias_a, w_eps,
                                                       b_eps, w_ana, out, apart);
        cand_kernel_f32<<<NC / 2 / 4, 256, 0, stream>>>(phi_p, emb_p, bias_p,
                                                        w_ana, b_ana, apart, out);
    }
}

// Round 3
// 290.088 us; speedup vs baseline: 1.2609x; 1.0246x over previous
//
#include <hip/hip_runtime.h>

// MentionRankingModel: h_a/h_p embedding-bag + tanh + linear scoring into
// a 512x512 score matrix (diag = eps scores, strict lower tri = ana scores).
//
// R1: cand gather is BW-bound on the L2-miss path -> bf16 table in d_ws.
// R2 accounting: dur_us = ~167us harness reset (fixed) + our kernels (~130us).
//   cand (89.5us) sits at the compulsory-miss x random-256B-BW floor.
//   Remaining slack is cvt (37us @ 4.15 TB/s) + kernel boundaries ->
//   fuse zero+mention+cvt into one prep dispatch, 64B/thread cvt.

static constexpr int NM = 512;                    // mentions
static constexpr int NF = 20;                     // features per mention/candidate
static constexpr int NC = NM * (NM - 1) / 2;      // 130816 candidates
static constexpr int H  = 128;                    // HA == HP == 128
static constexpr int EMBP_ROWS = 200001;
static constexpr long long EMBP_ELEMS = (long long)EMBP_ROWS * H;  // 25,600,128
static constexpr int NPAIR = (int)(EMBP_ELEMS / 16);               // 1,600,008 (exact)
static constexpr int CVT_BLOCKS = (NPAIR + 255) / 256;             // 6251
// prep dispatch layout: [0,64) zero-out, [64,128) mention, [128,128+CVT_BLOCKS) cvt
static constexpr int PREP_BLOCKS = 128 + CVT_BLOCKS;

__device__ __forceinline__ unsigned bf16_rne(float f) {
    unsigned u = __float_as_uint(f);
    return (u + 0x7fffu + ((u >> 16) & 1u)) >> 16;
}

__device__ __forceinline__ unsigned pack2(float lo, float hi) {
    return bf16_rne(lo) | (bf16_rne(hi) << 16);
}

__device__ __forceinline__ float reduce_half32(float v) {
    #pragma unroll
    for (int m = 16; m; m >>= 1) v += __shfl_xor(v, m, 64);
    return v;
}

// ---------------------------------------------------------------------------
// Fused prep: zero d_out, mention scores (diag + apart), emb_p f32->bf16.
__global__ __launch_bounds__(256) void prep_kernel(
        const int*   __restrict__ phi_a,  const float* __restrict__ emb_a,
        const float* __restrict__ bias_a, const float* __restrict__ w_eps,
        const float* __restrict__ b_eps,  const float* __restrict__ w_ana,
        const float* __restrict__ emb_p,  uint4* __restrict__ embp16,
        float* __restrict__ out, float* __restrict__ apart) {
    const int b = blockIdx.x;

    if (b >= 128) {
        // ---- cvt: emb_p f32 -> bf16, 16 elements (64 B read / 32 B write) per thread
        int i = (b - 128) * 256 + threadIdx.x;
        if (i < NPAIR) {
            const float4* s = (const float4*)emb_p + (size_t)i * 4;
            float4 a = s[0], c = s[1], d = s[2], e = s[3];
            uint4 o0, o1;
            o0.x = pack2(a.x, a.y); o0.y = pack2(a.z, a.w);
            o0.z = pack2(c.x, c.y); o0.w = pack2(c.z, c.w);
            o1.x = pack2(d.x, d.y); o1.y = pack2(d.z, d.w);
            o1.z = pack2(e.x, e.y); o1.w = pack2(e.z, e.w);
            uint4* dst = embp16 + (size_t)i * 2;
            dst[0] = o0; dst[1] = o1;
        }
        return;
    }

    if (b < 64) {
        // ---- zero the 512x512 output (poisoned 0xAA before every call)
        float4* o = (float4*)out;
        int t = b * 256 + threadIdx.x;          // [0, 16384)
        float4 z = make_float4(0.f, 0.f, 0.f, 0.f);
        #pragma unroll
        for (int r = 0; r < 4; ++r) o[t + r * 16384] = z;
        return;
    }

    // ---- mention scores: blocks [64,128), 2 mentions/wave, float4/lane
    const int lane = threadIdx.x & 63;
    const int half = lane >> 5;
    const int k    = lane & 31;
    const int wave = (b - 64) * 4 + (threadIdx.x >> 6);
    const int m    = wave * 2 + half;           // [0, 512)

    float4 acc = *(const float4*)(bias_a + k * 4);
    const int* prow = phi_a + m * NF;
    #pragma unroll
    for (int f = 0; f < NF; ++f) {
        int idx = prow[f];
        if (idx != 0) {                         // padding_idx = 0 contributes zero
            float4 v = *(const float4*)(emb_a + idx * H + k * 4);
            acc.x += v.x; acc.y += v.y; acc.z += v.z; acc.w += v.w;
        }
    }
    float4 h;
    h.x = tanhf(acc.x); h.y = tanhf(acc.y); h.z = tanhf(acc.z); h.w = tanhf(acc.w);

    float4 we = *(const float4*)(w_eps + k * 4);
    float4 wa = *(const float4*)(w_ana + k * 4);
    float eps = h.x*we.x + h.y*we.y + h.z*we.z + h.w*we.w;
    float ap  = h.x*wa.x + h.y*wa.y + h.z*wa.z + h.w*wa.w;
    eps = reduce_half32(eps);
    ap  = reduce_half32(ap);
    if (k == 0) {
        out[m * NM + m] = eps + b_eps[0];
        apart[m] = ap;
    }
}

// ---------------------------------------------------------------------------
// Candidates, bf16 table: 4 candidates/wave, 16 lanes each holding 8 elems.
// Each gather instruction: 64 lanes x 16 B = four full contiguous 256 B rows.
// BW-bound at the compulsory-L2-miss x random-256B-granule floor (R2 profile).
__global__ __launch_bounds__(256) void cand_kernel_bf16(
        const int* __restrict__ phi_p, const unsigned* __restrict__ embp,
        const float* __restrict__ bias_p, const float* __restrict__ w_ana,
        const float* __restrict__ b_ana, const float* __restrict__ apart,
        float* __restrict__ out) {
    const int lane = threadIdx.x & 63;
    const int g    = lane >> 4;
    const int k    = lane & 15;
    const int wave = (blockIdx.x * 256 + threadIdx.x) >> 6;
    const int c    = wave * 4 + g;             // grid exact: c in [0,130816)

    float4 b0 = *(const float4*)(bias_p + k * 8);
    float4 b1 = *(const float4*)(bias_p + k * 8 + 4);
    float a0 = b0.x, a1 = b0.y, a2 = b0.z, a3 = b0.w;
    float a4 = b1.x, a5 = b1.y, a6 = b1.z, a7 = b1.w;

    const int* prow = phi_p + c * NF;
    #pragma unroll
    for (int f = 0; f < NF; ++f) {
        int idx = prow[f];
        uint4 u = *(const uint4*)(embp + (size_t)idx * (H / 2) + k * 4);
        if (idx == 0) { u.x = 0; u.y = 0; u.z = 0; u.w = 0; }  // padding row
        a0 += __uint_as_float(u.x << 16); a1 += __uint_as_float(u.x & 0xffff0000u);
        a2 += __uint_as_float(u.y << 16); a3 += __uint_as_float(u.y & 0xffff0000u);
        a4 += __uint_as_float(u.z << 16); a5 += __uint_as_float(u.z & 0xffff0000u);
        a6 += __uint_as_float(u.w << 16); a7 += __uint_as_float(u.w & 0xffff0000u);
    }

    float4 w0 = *(const float4*)(w_ana + H + k * 8);
    float4 w1 = *(const float4*)(w_ana + H + k * 8 + 4);
    float part = tanhf(a0)*w0.x + tanhf(a1)*w0.y + tanhf(a2)*w0.z + tanhf(a3)*w0.w
               + tanhf(a4)*w1.x + tanhf(a5)*w1.y + tanhf(a6)*w1.z + tanhf(a7)*w1.w;
    #pragma unroll
    for (int m = 8; m; m >>= 1) part += __shfl_xor(part, m, 64);  // within 16-group

    if (k == 0) {
        float s = sqrtf((float)(8 * c + 1));
        int j = (int)((1.0f + s) * 0.5f);
        while (j * (j + 1) / 2 <= c) ++j;
        while (j * (j - 1) / 2 > c) --j;
        int col = c - j * (j - 1) / 2;
        out[j * NM + col] = part + apart[j] + b_ana[0];
    }
}

// ---------------------------------------------------------------------------
// f32 fallback (proven R1 kernels) in case ws_size can't hold the bf16 table.
__global__ __launch_bounds__(256) void zero_out_kernel(float4* __restrict__ out) {
    out[blockIdx.x * 256 + threadIdx.x] = make_float4(0.f, 0.f, 0.f, 0.f);
}

__global__ __launch_bounds__(256) void mention_kernel(
        const int*   __restrict__ phi_a,  const float* __restrict__ emb_a,
        const float* __restrict__ bias_a, const float* __restrict__ w_eps,
        const float* __restrict__ b_eps,  const float* __restrict__ w_ana,
        float* __restrict__ out, float* __restrict__ apart) {
    const int lane = threadIdx.x & 63;
    const int half = lane >> 5;
    const int k    = lane & 31;
    const int wave = (blockIdx.x * 256 + threadIdx.x) >> 6;
    const int m    = wave * 2 + half;

    float4 acc = *(const float4*)(bias_a + k * 4);
    const int* prow = phi_a + m * NF;
    #pragma unroll
    for (int f = 0; f < NF; ++f) {
        int idx = prow[f];
        if (idx != 0) {
            float4 v = *(const float4*)(emb_a + idx * H + k * 4);
            acc.x += v.x; acc.y += v.y; acc.z += v.z; acc.w += v.w;
        }
    }
    float4 h;
    h.x = tanhf(acc.x); h.y = tanhf(acc.y); h.z = tanhf(acc.z); h.w = tanhf(acc.w);

    float4 we = *(const float4*)(w_eps + k * 4);
    float4 wa = *(const float4*)(w_ana + k * 4);
    float eps = h.x*we.x + h.y*we.y + h.z*we.z + h.w*we.w;
    float ap  = h.x*wa.x + h.y*wa.y + h.z*wa.z + h.w*wa.w;
    eps = reduce_half32(eps);
    ap  = reduce_half32(ap);
    if (k == 0) {
        out[m * NM + m] = eps + b_eps[0];
        apart[m] = ap;
    }
}

__global__ __launch_bounds__(256) void cand_kernel_f32(
        const int*   __restrict__ phi_p,  const float* __restrict__ emb_p,
        const float* __restrict__ bias_p, const float* __restrict__ w_ana,
        const float* __restrict__ b_ana,  const float* __restrict__ apart,
        float* __restrict__ out) {
    const int lane = threadIdx.x & 63;
    const int half = lane >> 5;
    const int k    = lane & 31;
    const int wave = (blockIdx.x * 256 + threadIdx.x) >> 6;
    const int c    = wave * 2 + half;

    float4 acc = *(const float4*)(bias_p + k * 4);
    const int* prow = phi_p + c * NF;
    #pragma unroll
    for (int f = 0; f < NF; ++f) {
        int idx = prow[f];
        if (idx != 0) {
            float4 v = *(const float4*)(emb_p + idx * H + k * 4);
            acc.x += v.x; acc.y += v.y; acc.z += v.z; acc.w += v.w;
        }
    }
    float4 h;
    h.x = tanhf(acc.x); h.y = tanhf(acc.y); h.z = tanhf(acc.z); h.w = tanhf(acc.w);

    float4 w2 = *(const float4*)(w_ana + H + k * 4);
    float part = h.x*w2.x + h.y*w2.y + h.z*w2.z + h.w*w2.w;
    part = reduce_half32(part);

    if (k == 0) {
        float s = sqrtf((float)(8 * c + 1));
        int j = (int)((1.0f + s) * 0.5f);
        while (j * (j + 1) / 2 <= c) ++j;
        while (j * (j - 1) / 2 > c) --j;
        int col = c - j * (j - 1) / 2;
        out[j * NM + col] = part + apart[j] + b_ana[0];
    }
}

// ---------------------------------------------------------------------------
extern "C" void kernel_launch(void* const* d_in, const int* in_sizes, int n_in,
                              void* d_out, int out_size, void* d_ws, size_t ws_size,
                              hipStream_t stream) {
    const int*   phi_a  = (const int*)  d_in[0];
    const int*   phi_p  = (const int*)  d_in[1];
    const float* emb_a  = (const float*)d_in[2];
    const float* bias_a = (const float*)d_in[3];
    const float* emb_p  = (const float*)d_in[4];
    const float* bias_p = (const float*)d_in[5];
    const float* w_eps  = (const float*)d_in[6];
    const float* b_eps  = (const float*)d_in[7];
    const float* w_ana  = (const float*)d_in[8];
    const float* b_ana  = (const float*)d_in[9];
    float* out   = (float*)d_out;
    float* apart = (float*)d_ws;                       // 512 floats

    const size_t need = 4096 + (size_t)EMBP_ELEMS * 2; // apart pad + bf16 table
    const bool use_bf16 = ws_size >= need;

    if (use_bf16) {
        unsigned* embp16 = (unsigned*)((char*)d_ws + 4096);
        prep_kernel<<<PREP_BLOCKS, 256, 0, stream>>>(
            phi_a, emb_a, bias_a, w_eps, b_eps, w_ana,
            emb_p, (uint4*)embp16, out, apart);
        // 130816 candidates, 4/wave, 4 waves/block -> 8176 blocks (exact)
        cand_kernel_bf16<<<NC / 4 / 4, 256, 0, stream>>>(phi_p, embp16, bias_p,
                                                         w_ana, b_ana, apart, out);
    } else {
        zero_out_kernel<<<(NM * NM) / (4 * 256), 256, 0, stream>>>((float4*)out);
        mention_kernel<<<NM / 2 / 4, 256, 0, stream>>>(phi_a, emb_a, bias_a, w_eps,
                                                       b_eps, w_ana, out, apart);
        cand_kernel_f32<<<NC / 2 / 4, 256, 0, stream>>>(phi_p, emb_p, bias_p,
                                                        w_ana, b_ana, apart, out);
    }
}